// Round 18
// baseline (273.852 us; speedup 1.0000x reference)
//
#include <hip/hip_runtime.h>
#include <hip/hip_bf16.h>

// ---------------------------------------------------------------------------
// DAWN block on MI355X.  Round 18 = R17 + restore-GEMM rank-structure fold:
//  - wsf writes h_q/h_k/h_v (6MB) instead of s (48MB)
//  - gemm_rest: A = wr[n]*h computed in reg-staging (T14 split), B via gl_lds,
//    same single-phase counted-vmcnt 3-buffer schedule (vmcnt(6))
// ---------------------------------------------------------------------------

typedef __bf16 bf16_t;
typedef __bf16 bf16x4 __attribute__((ext_vector_type(4)));
typedef __bf16 bf16x8 __attribute__((ext_vector_type(8)));
typedef float f32x4 __attribute__((ext_vector_type(4)));

#define B_DIM 2
#define S_LEN 2048
#define D_DIM 1024
#define H_NUM 16
#define DH 64
#define N_NEU 8
#define R_DIM 256
#define KR_DIM 128
#define ROWS (B_DIM * S_LEN)   // 4096

static __device__ __forceinline__ void gl_lds16(const void* g, void* l)
{
    __builtin_amdgcn_global_load_lds(
        (__attribute__((address_space(1))) void*)(g),
        (__attribute__((address_space(3))) void*)(l), 16, 0, 0);
}

// ---------------------------------------------------------------------------
__global__ __launch_bounds__(256)
void tcast_kernel(const float* __restrict__ in, bf16_t* __restrict__ out, int I, int J)
{
    __shared__ float t[32][33];
    const int bJ = blockIdx.x * 32, bI = blockIdx.y * 32;
    const size_t boff = (size_t)blockIdx.z * I * J;
    const int tx = threadIdx.x, ty = threadIdx.y;
#pragma unroll
    for (int i = 0; i < 4; i++)
        t[ty * 4 + i][tx] = in[boff + (size_t)(bI + ty * 4 + i) * J + bJ + tx];
    __syncthreads();
#pragma unroll
    for (int i = 0; i < 4; i++)
        out[boff + (size_t)(bJ + ty * 4 + i) * I + bI + tx] = (bf16_t)t[tx][ty * 4 + i];
}

__global__ __launch_bounds__(256)
void tbf_kernel(const bf16_t* __restrict__ in, bf16_t* __restrict__ out, int I, int J)
{
    __shared__ bf16_t t[32][33];
    const int bJ = blockIdx.x * 32, bI = blockIdx.y * 32;
    const size_t boff = (size_t)blockIdx.z * I * J;
    const int tx = threadIdx.x, ty = threadIdx.y;
#pragma unroll
    for (int i = 0; i < 4; i++)
        t[ty * 4 + i][tx] = in[boff + (size_t)(bI + ty * 4 + i) * J + bJ + tx];
    __syncthreads();
#pragma unroll
    for (int i = 0; i < 4; i++)
        out[boff + (size_t)(bJ + ty * 4 + i) * I + bI + tx] = t[tx][ty * 4 + i];
}

__global__ __launch_bounds__(256)
void cast_kernel(const float* __restrict__ in, bf16_t* __restrict__ out, int n4)
{
    int i = blockIdx.x * 256 + threadIdx.x;
    if (i < n4) {
        float4 v = ((const float4*)in)[i];
        bf16_t* op = out + (size_t)i * 4;
        op[0] = (bf16_t)v.x; op[1] = (bf16_t)v.y; op[2] = (bf16_t)v.z; op[3] = (bf16_t)v.w;
    }
}

// ---------------------------------------------------------------------------
__global__ __launch_bounds__(256)
void ln_kernel(const float* __restrict__ x, const float* __restrict__ g,
               const float* __restrict__ beta, bf16_t* __restrict__ out)
{
    __shared__ float red[4];
    const int row = blockIdx.x;
    const int tid = threadIdx.x;
    float4 v = *(const float4*)&x[(size_t)row * D_DIM + tid * 4];

    float s = v.x + v.y + v.z + v.w;
#pragma unroll
    for (int o = 32; o; o >>= 1) s += __shfl_down(s, o);
    if ((tid & 63) == 0) red[tid >> 6] = s;
    __syncthreads();
    float mean = (red[0] + red[1] + red[2] + red[3]) * (1.f / D_DIM);
    __syncthreads();

    float dx = v.x - mean, dy = v.y - mean, dz = v.z - mean, dw = v.w - mean;
    float q = dx * dx + dy * dy + dz * dz + dw * dw;
#pragma unroll
    for (int o = 32; o; o >>= 1) q += __shfl_down(q, o);
    if ((tid & 63) == 0) red[tid >> 6] = q;
    __syncthreads();
    float var = (red[0] + red[1] + red[2] + red[3]) * (1.f / D_DIM);
    float rstd = rsqrtf(var + 1e-5f);

    float4 gv = *(const float4*)&g[tid * 4];
    float4 bv = *(const float4*)&beta[tid * 4];
    bf16_t* op = out + (size_t)row * D_DIM + tid * 4;
    op[0] = (bf16_t)(dx * rstd * gv.x + bv.x);
    op[1] = (bf16_t)(dy * rstd * gv.y + bv.y);
    op[2] = (bf16_t)(dz * rstd * gv.z + bv.z);
    op[3] = (bf16_t)(dw * rstd * gv.w + bv.w);
}

__global__ __launch_bounds__(256)
void ln2x_kernel(const float* __restrict__ x, const bf16_t* __restrict__ P0,
                 const bf16_t* __restrict__ P1, const float* __restrict__ g,
                 const float* __restrict__ beta, float* __restrict__ outf,
                 bf16_t* __restrict__ outn)
{
    __shared__ float red[4];
    const int row = blockIdx.x;
    const int tid = threadIdx.x;
    const size_t base = (size_t)row * D_DIM + tid * 4;
    float4 v  = *(const float4*)&x[base];
    bf16x4 p0 = *(const bf16x4*)&P0[base];
    bf16x4 p1 = *(const bf16x4*)&P1[base];
    v.x += (float)p0[0] + (float)p1[0];
    v.y += (float)p0[1] + (float)p1[1];
    v.z += (float)p0[2] + (float)p1[2];
    v.w += (float)p0[3] + (float)p1[3];
    *(float4*)&outf[base] = v;

    float s = v.x + v.y + v.z + v.w;
#pragma unroll
    for (int o = 32; o; o >>= 1) s += __shfl_down(s, o);
    if ((tid & 63) == 0) red[tid >> 6] = s;
    __syncthreads();
    float mean = (red[0] + red[1] + red[2] + red[3]) * (1.f / D_DIM);
    __syncthreads();

    float dx = v.x - mean, dy = v.y - mean, dz = v.z - mean, dw = v.w - mean;
    float q = dx * dx + dy * dy + dz * dz + dw * dw;
#pragma unroll
    for (int o = 32; o; o >>= 1) q += __shfl_down(q, o);
    if ((tid & 63) == 0) red[tid >> 6] = q;
    __syncthreads();
    float var = (red[0] + red[1] + red[2] + red[3]) * (1.f / D_DIM);
    float rstd = rsqrtf(var + 1e-5f);

    float4 gv = *(const float4*)&g[tid * 4];
    float4 bv = *(const float4*)&beta[tid * 4];
    bf16_t* op = outn + base;
    op[0] = (bf16_t)(dx * rstd * gv.x + bv.x);
    op[1] = (bf16_t)(dy * rstd * gv.y + bv.y);
    op[2] = (bf16_t)(dz * rstd * gv.z + bv.z);
    op[3] = (bf16_t)(dw * rstd * gv.w + bv.w);
}

// ---------------------------------------------------------------------------
// Fused weighted-sum: writes h_q/h_k/h_v only (wr-scaling folded into GEMM).
// ---------------------------------------------------------------------------
__global__ __launch_bounds__(256)
void wsf_kernel(const bf16_t* __restrict__ y,
                const float* __restrict__ wfQ, const float* __restrict__ wfK,
                const float* __restrict__ wfV,
                bf16_t* __restrict__ hq, bf16_t* __restrict__ hk, bf16_t* __restrict__ hv)
{
    const int r = threadIdx.x;
    const int row = blockIdx.x;
    const bf16_t* yrow = y + (size_t)row * 4096;
    const float* fQ = wfQ + row * N_NEU;
    const float* fK = wfK + row * N_NEU;
    const float* fV = wfV + row * N_NEU;
    float aQ = 0.f, aK = 0.f, aV = 0.f;
#pragma unroll
    for (int n = 0; n < N_NEU; n++) {
        float yq = (float)yrow[n * R_DIM + r];
        float yv = (float)yrow[2048 + n * R_DIM + r];
        aQ += fQ[n] * yq;
        aK += fK[n] * yq;
        aV += fV[n] * yv;
    }
    const size_t idx = (size_t)row * R_DIM + r;
    hq[idx] = (bf16_t)aQ;
    hk[idx] = (bf16_t)aK;
    hv[idx] = (bf16_t)aV;
}

// know-path ws with fused split-K reduce (2 rows/block, 2048 blocks).
__global__ __launch_bounds__(256)
void ws2_kernel(const bf16_t* __restrict__ P0, const bf16_t* __restrict__ P1,
                const float* __restrict__ wf, const float* __restrict__ wr,
                bf16_t* __restrict__ sout)
{
    const int lr = threadIdx.x >> 7;
    const int r  = threadIdx.x & 127;
    const int row = blockIdx.x * 2 + lr;
    const size_t rb = (size_t)row * (N_NEU * KR_DIM);
    const float* wfp = wf + row * N_NEU;
    const float* wrp = wr + row * N_NEU;
    float acc = 0.f;
#pragma unroll
    for (int n = 0; n < N_NEU; n++) {
        size_t i = rb + n * KR_DIM + r;
        acc += wfp[n] * ((float)P0[i] + (float)P1[i]);
    }
    bf16_t* srow = sout + rb;
#pragma unroll
    for (int n = 0; n < N_NEU; n++) srow[n * KR_DIM + r] = (bf16_t)(wrp[n] * acc);
}

// ---------------------------------------------------------------------------
// gemm_rest: QKV[12288][1024] = (wr*h)[12288][2048] @ Bsel[1024][2048]^T.
// 256x256 block, 8 waves (2Mx4N), BK=32, 3-buffer counted-vmcnt pipeline.
// A reg-staged from h (bf16, [12288][256]) * wr (f32 [4096][8]); B via gl_lds
// with pre-swizzled source.  A write-side swizzle == read swizzle.
// stage_load(t2): 2 h-loads + 2 wr-loads + 2 B gl_lds  (6 vmem)
// stage_write(t1): cvt/mul + 2 ds_write_b128 (regs loaded last iter, T14)
// Wait per iter: vmcnt(6) lgkmcnt(0) -> oldest 2 = tile-t B loads landed.
// ---------------------------------------------------------------------------
__global__ __launch_bounds__(512, 1)
void gemm_rest_kernel(const bf16_t* __restrict__ H,
                      const float* __restrict__ wQ, const float* __restrict__ wK,
                      const float* __restrict__ wV,
                      const bf16_t* __restrict__ Bt, const bf16_t* __restrict__ Bt2,
                      bf16_t* __restrict__ Cout, int M, int N, int K)
{
    __shared__ bf16_t As[3][256][32];
    __shared__ bf16_t Bs[3][256][32];
    const int tid = threadIdx.x;
    const int l = tid & 63, w = tid >> 6;
    const int wrw = w >> 2;             // 0..1 (M half)
    const int wc  = w & 3;              // 0..3 (N quarter)

    const int nbxy = gridDim.x * gridDim.y;
    int bid = blockIdx.y * gridDim.x + blockIdx.x;
    if ((nbxy & 7) == 0) bid = (bid & 7) * (nbxy >> 3) + (bid >> 3);
    const int bx = bid % gridDim.x, by = bid / gridDim.x;

    const int m0 = by * 256, n0 = bx * 256;
    const bf16_t* Bsel = (by < 32) ? Bt : Bt2;
    const float*  Wsel = (by < 16) ? wQ : ((by < 32) ? wK : wV);
    const int mloc = m0 & 4095;         // stream-local row base

    const int strow = w * 16 + (l >> 2);          // 0..127
    const int ccolb = (l & 3) * 16;               // byte col within 64B row
    const int swzb  = ccolb ^ ((strow & 6) << 3); // write/read swizzle (row+128 same)
    const int scelem = swzb >> 1;                 // pre-swizzled B source col
    const bf16_t* Bg0 = Bsel + (size_t)(n0 + strow) * K + scelem;
    const bf16_t* Bg1 = Bsel + (size_t)(n0 + strow + 128) * K + scelem;
    const bf16_t* Hg0 = H + (size_t)(m0 + strow) * 256 + (ccolb >> 1);
    const bf16_t* Hg1 = H + (size_t)(m0 + strow + 128) * 256 + (ccolb >> 1);
    const float* Wg0 = Wsel + (size_t)(mloc + strow) * 8;
    const float* Wg1 = Wsel + (size_t)(mloc + strow + 128) * 8;

    bf16x8 ha, hb;
    float wa, wb;
    auto stage_load = [&](int t2) {
        const int r0 = (t2 & 7) * 32;
        const int np = t2 >> 3;
        ha = *(const bf16x8*)(Hg0 + r0);
        hb = *(const bf16x8*)(Hg1 + r0);
        wa = Wg0[np];
        wb = Wg1[np];
        char* dB = (char*)&Bs[t2 % 3][0][0] + w * 1024;
        gl_lds16(Bg0 + t2 * 32, dB);
        gl_lds16(Bg1 + t2 * 32, dB + 8192);
    };
    auto stage_write = [&](int t1) {
        const int buf = t1 % 3;
        bf16x8 sa, sb;
#pragma unroll
        for (int e = 0; e < 8; e++) {
            sa[e] = (bf16_t)(wa * (float)ha[e]);
            sb[e] = (bf16_t)(wb * (float)hb[e]);
        }
        *(bf16x8*)((char*)&As[buf][strow][0] + swzb) = sa;
        *(bf16x8*)((char*)&As[buf][strow + 128][0] + swzb) = sb;
    };

    f32x4 acc[8][4];
    const f32x4 zero = {0.f, 0.f, 0.f, 0.f};
#pragma unroll
    for (int i = 0; i < 8; i++)
#pragma unroll
        for (int j = 0; j < 4; j++) acc[i][j] = zero;

    const int fr  = l & 15;
    const int fkb = (l >> 4) * 16;

    // prologue: tile0 fully staged, tile1 loads in flight
    stage_load(0);
    stage_write(0);          // waits h(t0) via reg dep
    stage_load(1);

    const int nK = K >> 5;   // 64
    for (int it = 0; it < nK; ++it) {
        if (it + 1 < nK) {
            asm volatile("s_waitcnt vmcnt(6) lgkmcnt(0)" ::: "memory");
        } else {
            asm volatile("s_waitcnt vmcnt(0) lgkmcnt(0)" ::: "memory");
        }
        __builtin_amdgcn_s_barrier();
        __builtin_amdgcn_sched_barrier(0);

        const int cur = it % 3;
        const char* Ab = (const char*)&As[cur][0][0];
        const char* Bb = (const char*)&Bs[cur][0][0];
        bf16x8 af[8], bv[4];
#pragma unroll
        for (int i = 0; i < 8; i++) {
            const int rowA = wrw * 128 + i * 16 + fr;
            af[i] = *(const bf16x8*)(Ab + rowA * 64 + (fkb ^ ((rowA & 6) << 3)));
        }
#pragma unroll
        for (int i = 0; i < 4; i++) {
            const int rowB = wc * 64 + i * 16 + fr;
            bv[i] = *(const bf16x8*)(Bb + rowB * 64 + (fkb ^ ((rowB & 6) << 3)));
        }

        if (it + 1 < nK) stage_write(it + 1);   // ds_writes to buf (it+1)%3 != cur
        if (it + 2 < nK) stage_load(it + 2);

        __builtin_amdgcn_s_setprio(1);
#pragma unroll
        for (int mi = 0; mi < 8; mi++)
#pragma unroll
            for (int ni = 0; ni < 4; ni++)
                acc[mi][ni] = __builtin_amdgcn_mfma_f32_16x16x32_bf16(af[mi], bv[ni], acc[mi][ni], 0, 0, 0);
        __builtin_amdgcn_s_setprio(0);
    }

    const int orow = (l >> 4) * 4;
    const int ocol = l & 15;
#pragma unroll
    for (int mi = 0; mi < 8; mi++)
#pragma unroll
        for (int ni = 0; ni < 4; ni++)
#pragma unroll
            for (int j = 0; j < 4; j++) {
                int row = m0 + wrw * 128 + mi * 16 + orow + j;
                int col = n0 + wc * 64 + ni * 16 + ocol;
                Cout[(size_t)row * N + col] = (bf16_t)acc[mi][ni][j];
            }
}

// ---------------------------------------------------------------------------
// gemm256sq: 256x256 block (feature GEMM).  R17-proven.
// ---------------------------------------------------------------------------
__global__ __launch_bounds__(512, 1)
void gemm256sq_kernel(const bf16_t* __restrict__ A, const bf16_t* __restrict__ Bt,
                      const bf16_t* __restrict__ Bt2, int splitMy,
                      bf16_t* __restrict__ Cout, int M, int N, int K)
{
    __shared__ bf16_t As[3][256][32];
    __shared__ bf16_t Bs[3][256][32];
    const int tid = threadIdx.x;
    const int l = tid & 63, w = tid >> 6;
    const int wr = w >> 2;
    const int wc = w & 3;

    const int nbxy = gridDim.x * gridDim.y;
    int bid = blockIdx.y * gridDim.x + blockIdx.x;
    if ((nbxy & 7) == 0) bid = (bid & 7) * (nbxy >> 3) + (bid >> 3);
    const int bx = bid % gridDim.x, by = bid / gridDim.x;

    const int m0 = by * 256, n0 = bx * 256;
    const bf16_t* Bsel = (by < splitMy) ? Bt : Bt2;

    const int strow  = w * 16 + (l >> 2);
    const int scelem = ((((l & 3) * 16) ^ ((strow & 6) << 3)) >> 1);
    const bf16_t* Ag0 = A    + (size_t)(m0 + strow) * K + scelem;
    const bf16_t* Ag1 = A    + (size_t)(m0 + strow + 128) * K + scelem;
    const bf16_t* Bg0 = Bsel + (size_t)(n0 + strow) * K + scelem;
    const bf16_t* Bg1 = Bsel + (size_t)(n0 + strow + 128) * K + scelem;

    auto stage = [&](int buf, int k0) {
        char* dA = (char*)&As[buf][0][0] + w * 1024;
        char* dB = (char*)&Bs[buf][0][0] + w * 1024;
        gl_lds16(Ag0 + k0, dA);
        gl_lds16(Ag1 + k0, dA + 8192);
        gl_lds16(Bg0 + k0, dB);
        gl_lds16(Bg1 + k0, dB + 8192);
    };

    f32x4 acc[8][4];
    const f32x4 zero = {0.f, 0.f, 0.f, 0.f};
#pragma unroll
    for (int i = 0; i < 8; i++)
#pragma unroll
        for (int j = 0; j < 4; j++) acc[i][j] = zero;

    const int fr  = l & 15;
    const int fkb = (l >> 4) * 16;

    stage(0, 0);
    stage(1, 32);

    const int nK = K >> 5;
    for (int it = 0; it < nK; ++it) {
        if (it + 1 < nK) {
            asm volatile("s_waitcnt vmcnt(4)" ::: "memory");
        } else {
            asm volatile("s_waitcnt vmcnt(0)" ::: "memory");
        }
        __builtin_amdgcn_s_barrier();
        __builtin_amdgcn_sched_barrier(0);

        const int cur = it % 3;
        const char* Ab = (const char*)&As[cur][0][0];
        const char* Bb = (const char*)&Bs[cur][0][0];
        bf16x8 af[8], bv[4];
#pragma unroll
        for (int i = 0; i < 8; i++) {
            const int rowA = wr * 128 + i * 16 + fr;
            af[i] = *(const bf16x8*)(Ab + rowA * 64 + (fkb ^ ((rowA & 6) << 3)));
        }
#pragma unroll
        for (int i = 0; i < 4; i++) {
            const int rowB = wc * 64 + i * 16 + fr;
            bv[i] = *(const bf16x8*)(Bb + rowB * 64 + (fkb ^ ((rowB & 6) << 3)));
        }

        if (it + 2 < nK) stage((it + 2) % 3, (it + 2) * 32);

        __builtin_amdgcn_s_setprio(1);
#pragma unroll
        for (int mi = 0; mi < 8; mi++)
#pragma unroll
            for (int ni = 0; ni < 4; ni++)
                acc[mi][ni] = __builtin_amdgcn_mfma_f32_16x16x32_bf16(af[mi], bv[ni], acc[mi][ni], 0, 0, 0);
        __builtin_amdgcn_s_setprio(0);
    }

    const int orow = (l >> 4) * 4;
    const int ocol = l & 15;
#pragma unroll
    for (int mi = 0; mi < 8; mi++)
#pragma unroll
        for (int ni = 0; ni < 4; ni++)
#pragma unroll
            for (int j = 0; j < 4; j++) {
                int row = m0 + wr * 128 + mi * 16 + orow + j;
                int col = n0 + wc * 64 + ni * 16 + ocol;
                Cout[(size_t)row * N + col] = (bf16_t)acc[mi][ni][j];
            }
}

// ---------------------------------------------------------------------------
// gemm256: 256x128 tile, EPI=2 split-K (bf16 partials).  R12-proven.
// ---------------------------------------------------------------------------
template<int EPI>
__global__ __launch_bounds__(512, 2)
void gemm256_kernel(const bf16_t* __restrict__ A, const bf16_t* __restrict__ Bt,
                    const bf16_t* __restrict__ Bt2, int splitMy,
                    void* Cout, int M, int N, int K)
{
    __shared__ bf16_t As[3][256][32];
    __shared__ bf16_t Bs[3][128][32];
    const int tid = threadIdx.x;
    const int l = tid & 63, w = tid >> 6;
    const int wr = w >> 1, wc = w & 1;

    const int nbxy = gridDim.x * gridDim.y;
    int bid = blockIdx.y * gridDim.x + blockIdx.x;
    if ((nbxy & 7) == 0) bid = (bid & 7) * (nbxy >> 3) + (bid >> 3);
    const int bx = bid % gridDim.x, by = bid / gridDim.x;

    const int m0 = by * 256, n0 = bx * 128;
    const bf16_t* Bsel = (by < splitMy) ? Bt : Bt2;

    int kbeg = 0, kend = K;
    if constexpr (EPI == 2) { const int half = K >> 1; kbeg = blockIdx.z * half; kend = kbeg + half; }

    const int strow  = w * 16 + (l >> 2);
    const int scelem = ((((l & 3) * 16) ^ ((strow & 6) << 3)) >> 1);
    const bf16_t* Ag0 = A    + (size_t)(m0 + strow) * K + scelem;
    const bf16_t* Ag1 = A    + (size_t)(m0 + strow + 128) * K + scelem;
    const bf16_t* Bg0 = Bsel + (size_t)(n0 + strow) * K + scelem;

    auto stage = [&](int buf, int k0) {
        char* dA = (char*)&As[buf][0][0] + w * 1024;
        char* dB = (char*)&Bs[buf][0][0] + w * 1024;
        gl_lds16(Ag0 + k0, dA);
        gl_lds16(Ag1 + k0, dA + 8192);
        gl_lds16(Bg0 + k0, dB);
    };

    f32x4 acc[4][4];
    const f32x4 zero = {0.f, 0.f, 0.f, 0.f};
#pragma unroll
    for (int i = 0; i < 4; i++)
#pragma unroll
        for (int j = 0; j < 4; j++) acc[i][j] = zero;

    const int fr  = l & 15;
    const int fkb = (l >> 4) * 16;

    stage(0, kbeg);
    stage(1, kbeg + 32);

    const int nK = (kend - kbeg) >> 5;
    for (int it = 0; it < nK; ++it) {
        if (it + 1 < nK) {
            asm volatile("s_waitcnt vmcnt(3)" ::: "memory");
        } else {
            asm volatile("s_waitcnt vmcnt(0)" ::: "memory");
        }
        __builtin_amdgcn_s_barrier();
        __builtin_amdgcn_sched_barrier(0);

        const int cur = it % 3;
        const char* Ab = (const char*)&As[cur][0][0];
        const char* Bb = (const char*)&Bs[cur][0][0];
        bf16x8 af[4], bv[4];
#pragma unroll
        for (int i = 0; i < 4; i++) {
            const int rowA = wr * 64 + i * 16 + fr;
            af[i] = *(const bf16x8*)(Ab + rowA * 64 + (fkb ^ ((rowA & 6) << 3)));
        }
#pragma unroll
        for (int i = 0; i < 4; i++) {
            const int rowB = wc * 64 + i * 16 + fr;
            bv[i] = *(const bf16x8*)(Bb + rowB * 64 + (fkb ^ ((rowB & 6) << 3)));
        }

        if (it + 2 < nK) stage((it + 2) % 3, kbeg + (it + 2) * 32);

        __builtin_amdgcn_s_setprio(1);
#pragma unroll
        for (int mi = 0; mi < 4; mi++)
#pragma unroll
            for (int ni = 0; ni < 4; ni++)
                acc[mi][ni] = __builtin_amdgcn_mfma_f32_16x16x32_bf16(af[mi], bv[ni], acc[mi][ni], 0, 0, 0);
        __builtin_amdgcn_s_setprio(0);
    }

    const int orow = (l >> 4) * 4;
    const int ocol = l & 15;
#pragma unroll
    for (int mi = 0; mi < 4; mi++)
#pragma unroll
        for (int ni = 0; ni < 4; ni++)
#pragma unroll
            for (int j = 0; j < 4; j++) {
                int row = m0 + wr * 64 + mi * 16 + orow + j;
                int col = n0 + wc * 64 + ni * 16 + ocol;
                size_t idx = (size_t)row * N + col;
                if constexpr (EPI == 0) {
                    ((bf16_t*)Cout)[idx] = (bf16_t)acc[mi][ni][j];
                } else {
                    ((bf16_t*)Cout)[(size_t)blockIdx.z * M * N + idx] = (bf16_t)acc[mi][ni][j];
                }
            }
}

// ---------------------------------------------------------------------------
// Legacy 128x128 GEMM (EPI=1 only: fp32 C = acc + resid).
// ---------------------------------------------------------------------------
template<int EPI>
__global__ __launch_bounds__(256)
void gemm_kernel(const bf16_t* __restrict__ A, const bf16_t* __restrict__ Bt,
                 const bf16_t* __restrict__ Bt2, int splitMy,
                 void* Cout, const float* resid, int M, int N, int K)
{
    __shared__ bf16_t As[3][128][32];
    __shared__ bf16_t Bs[3][128][32];
    const int tid = threadIdx.x;
    const int l = tid & 63, w = tid >> 6;
    const int wr = w >> 1, wc = w & 1;

    const int nbxy = gridDim.x * gridDim.y;
    int bid = blockIdx.y * gridDim.x + blockIdx.x;
    if ((nbxy & 7) == 0) bid = (bid & 7) * (nbxy >> 3) + (bid >> 3);
    const int bx = bid % gridDim.x, by = bid / gridDim.x;

    const int m0 = by * 128, n0 = bx * 128;
    const bf16_t* Bsel = (by < splitMy) ? Bt : Bt2;

    const int kbeg = 0, kend = K;

    const int srow = l >> 2;
    const int scolswz = (((l & 3) * 16) ^ ((srow & 6) << 3)) >> 1;
    const bf16_t* Ag0 = A    + (size_t)(m0 + w * 32 + srow) * K + scolswz;
    const bf16_t* Ag1 = Ag0 + (size_t)16 * K;
    const bf16_t* Bg0 = Bsel + (size_t)(n0 + w * 32 + srow) * K + scolswz;
    const bf16_t* Bg1 = Bg0 + (size_t)16 * K;

    auto stage = [&](int buf, int k0) {
        char* Asb = (char*)&As[buf][0][0] + w * 2048;
        char* Bsb = (char*)&Bs[buf][0][0] + w * 2048;
        gl_lds16(Ag0 + k0, Asb);
        gl_lds16(Ag1 + k0, Asb + 1024);
        gl_lds16(Bg0 + k0, Bsb);
        gl_lds16(Bg1 + k0, Bsb + 1024);
    };

    f32x4 acc[4][4];
    const f32x4 zero = {0.f, 0.f, 0.f, 0.f};
#pragma unroll
    for (int i = 0; i < 4; i++)
#pragma unroll
        for (int j = 0; j < 4; j++) acc[i][j] = zero;

    const int fr = l & 15;
    const int fkb = (l >> 4) * 16;

    stage(0, kbeg);
    stage(1, kbeg + 32);

    const int nK = (kend - kbeg) >> 5;
    for (int it = 0; it < nK; ++it) {
        if (it + 1 < nK) {
            asm volatile("s_waitcnt vmcnt(4)" ::: "memory");
        } else {
            asm volatile("s_waitcnt vmcnt(0)" ::: "memory");
        }
        __builtin_amdgcn_s_barrier();
        __builtin_amdgcn_sched_barrier(0);

        const int cur = it % 3;
        const char* Ab = (const char*)&As[cur][0][0];
        const char* Bb = (const char*)&Bs[cur][0][0];
        bf16x8 af[4], bv[4];
#pragma unroll
        for (int i = 0; i < 4; i++) {
            const int rowA = wr * 64 + i * 16 + fr;
            af[i] = *(const bf16x8*)(Ab + rowA * 64 + (fkb ^ ((rowA & 6) << 3)));
        }
#pragma unroll
        for (int i = 0; i < 4; i++) {
            const int rowB = wc * 64 + i * 16 + fr;
            bv[i] = *(const bf16x8*)(Bb + rowB * 64 + (fkb ^ ((rowB & 6) << 3)));
        }

        if (it + 2 < nK) stage((it + 2) % 3, kbeg + (it + 2) * 32);

        __builtin_amdgcn_s_setprio(1);
#pragma unroll
        for (int mi = 0; mi < 4; mi++)
#pragma unroll
            for (int ni = 0; ni < 4; ni++)
                acc[mi][ni] = __builtin_amdgcn_mfma_f32_16x16x32_bf16(af[mi], bv[ni], acc[mi][ni], 0, 0, 0);
        __builtin_amdgcn_s_setprio(0);
    }

    const int orow = (l >> 4) * 4;
    const int ocol = l & 15;
#pragma unroll
    for (int mi = 0; mi < 4; mi++)
#pragma unroll
        for (int ni = 0; ni < 4; ni++)
#pragma unroll
            for (int j = 0; j < 4; j++) {
                int row = m0 + wr * 64 + mi * 16 + orow + j;
                int col = n0 + wc * 64 + ni * 16 + ocol;
                size_t idx = (size_t)row * N + col;
                ((float*)Cout)[idx] = acc[mi][ni][j] + resid[idx];
            }
}

// ---------------------------------------------------------------------------
// Causal flash attention v2 (R16, unchanged).
// ---------------------------------------------------------------------------
__global__ __launch_bounds__(512)
void fa_kernel(const bf16_t* __restrict__ Q, const bf16_t* __restrict__ K,
               const bf16_t* __restrict__ Vt, bf16_t* __restrict__ O)
{
    __shared__ bf16_t Ks[2][64][64];
    __shared__ bf16_t Vs[2][64][64];
    __shared__ bf16_t Ps[8][16][72];

    const int tid = threadIdx.x;
    const int l = tid & 63, w = tid >> 6;   // 8 waves

    const int bid  = blockIdx.x;
    const int xcd  = bid & 7;
    const int slot = bid >> 3;          // 0..63
    const int head = slot & 3;
    const int j16  = slot >> 2;         // 0..15
    const int p    = (j16 < 8) ? j16 : (23 - j16);   // pair (j,15-j) per CU
    const int bh   = xcd * 4 + head;
    const int b = bh >> 4, h = bh & 15;
    const int q0 = p * 128;
    const int nt = 2 * p + 2;           // 64-key tiles

    const bf16_t* Qp = Q + (size_t)b * S_LEN * D_DIM + h * DH;
    const bf16_t* Kp = K + (size_t)b * S_LEN * D_DIM + h * DH;
    const bf16_t* Vp = Vt + (size_t)b * D_DIM * S_LEN + (size_t)h * DH * S_LEN;

    const int fr = l & 15, fg = l >> 4, fk = fg * 8;

    const int srow = tid >> 3;                 // 0..63
    const int scel = 8 * ((tid & 7) ^ (srow & 7));   // swizzled col (elems)
    const bf16_t* Kst = Kp + (size_t)srow * D_DIM + scel;
    const bf16_t* Vst = Vp + (size_t)srow * S_LEN + scel;
    char* KdA = (char*)&Ks[0][w * 8][0];
    char* KdB = (char*)&Ks[1][w * 8][0];
    char* VdA = (char*)&Vs[0][w * 8][0];
    char* VdB = (char*)&Vs[1][w * 8][0];

    bf16x8 ones8;
#pragma unroll
    for (int i = 0; i < 8; i++) ones8[i] = (bf16_t)1.f;

    const f32x4 zero = {0.f, 0.f, 0.f, 0.f};
    const float C_LOG2 = 0.125f * 1.44269504f;   // 1/sqrt(DH) * log2(e)

    bf16x8 qf[2];
#pragma unroll
    for (int ks = 0; ks < 2; ks++)
        qf[ks] = *(const bf16x8*)(Qp + (size_t)(q0 + w * 16 + fr) * D_DIM + ks * 32 + fk);

    f32x4 o[4];
    f32x4 la = zero;
    float m_r[4];
#pragma unroll
    for (int j = 0; j < 4; j++) { o[j] = zero; m_r[j] = -1e30f; }

    const int wq_hi = q0 + w * 16 + 15;
    const int wq_lo = q0 + w * 16;

    gl_lds16(Kst, KdA);
    gl_lds16(Vst, VdA);

    for (int t = 0; t < nt; t++) {
        __syncthreads();
        if (t + 1 < nt) {
            const size_t kn = (size_t)(t + 1) * 64;
            gl_lds16(Kst + kn * D_DIM, ((t + 1) & 1) ? KdB : KdA);
            gl_lds16(Vst + kn,         ((t + 1) & 1) ? VdB : VdA);
        }

        const int k0 = t * 64;
        if (k0 > wq_hi) continue;
        const int cur = t & 1;
        const char* Kb = (const char*)&Ks[cur][0][0];
        const char* Vb = (const char*)&Vs[cur][0][0];
        const int rswz = (fr & 7) << 4;

        f32x4 sc[4];
#pragma unroll
        for (int ni = 0; ni < 4; ni++) sc[ni] = zero;
        __builtin_amdgcn_s_setprio(1);
#pragma unroll
        for (int ks = 0; ks < 2; ks++) {
#pragma unroll
            for (int ni = 0; ni < 4; ni++) {
                bf16x8 kf = *(const bf16x8*)(Kb + (ni * 16 + fr) * 128
                                               + ((ks * 64 + fg * 16) ^ rswz));
                sc[ni] = __builtin_amdgcn_mfma_f32_16x16x32_bf16(qf[ks], kf, sc[ni], 0, 0, 0);
            }
        }
        __builtin_amdgcn_s_setprio(0);

        float pp[4][4];
        if (k0 + 63 >= wq_lo) {
#pragma unroll
            for (int ni = 0; ni < 4; ni++) {
                const int key = k0 + ni * 16 + fr;
#pragma unroll
                for (int j = 0; j < 4; j++) {
                    const int qg = wq_lo + fg * 4 + j;
                    pp[ni][j] = (key <= qg) ? sc[ni][j] * C_LOG2 : -1e30f;
                }
            }
        } else {
#pragma unroll
            for (int ni = 0; ni < 4; ni++)
#pragma unroll
                for (int j = 0; j < 4; j++)
                    pp[ni][j] = sc[ni][j] * C_LOG2;
        }

        float pmax[4];
#pragma unroll
        for (int j = 0; j < 4; j++)
            pmax[j] = fmaxf(fmaxf(pp[0][j], pp[1][j]), fmaxf(pp[2][j], pp[3][j]));
        bool need = (pmax[0] > m_r[0] + 8.f) || (pmax[1] > m_r[1] + 8.f) ||
                    (pmax[2] > m_r[2] + 8.f) || (pmax[3] > m_r[3] + 8.f);
        if (__any(need)) {
#pragma unroll
            for (int j = 0; j < 4; j++) {
                float rmax = pmax[j];
#pragma unroll
                for (int d = 1; d < 16; d <<= 1) rmax = fmaxf(rmax, __shfl_xor(rmax, d));
                if (rmax > m_r[j] + 8.f) {
                    float scale = exp2f(m_r[j] - rmax);
                    la[j] *= scale;
#pragma unroll
                    for (int nc = 0; nc < 4; nc++) o[nc][j] *= scale;
                    m_r[j] = rmax;
                }
            }
        }
#pragma unroll
        for (int j = 0; j < 4; j++)
#pragma unroll
            for (int ni = 0; ni < 4; ni++)
                pp[ni][j] = exp2f(pp[ni][j] - m_r[j]);

#pragma unroll
        for (int ni = 0; ni < 4; ni++)
#pragma unroll
            for (int j = 0; j < 4; j++)
                Ps[w][fg * 4 + j][ni * 16 + fr] = (bf16_t)pp[ni][j];

        __builtin_amdgcn_s_setprio(1);
#pragma unroll
        for (int ks = 0; ks < 2; ks++) {
            bf16x8 pa = *(const bf16x8*)&Ps[w][fr][ks * 32 + fk];
            la = __builtin_amdgcn_mfma_f32_16x16x32_bf16(pa, ones8, la, 0, 0, 0);
#pragma unroll
            for (int nc = 0; nc < 4; nc++) {
                bf16x8 vf = *(const bf16x8*)(Vb + (nc * 16 + fr) * 128
                                               + ((ks * 64 + fg * 16) ^ rswz));
                o[nc] = __builtin_amdgcn_mfma_f32_16x16x32_bf16(pa, vf, o[nc], 0, 0, 0);
            }
        }
        __builtin_amdgcn_s_setprio(0);
    }

#pragma unroll
    for (int j = 0; j < 4; j++) {
        const float inv = 1.f / la[j];
        const int q = wq_lo + fg * 4 + j;
        bf16_t* op = O + (size_t)(b * S_LEN + q) * D_DIM + h * DH;
#pragma unroll
        for (int nc = 0; nc < 4; nc++)
            op[nc * 16 + fr] = (bf16_t)(o[nc][j] * inv);
    }
}

// ---------------------------------------------------------------------------
extern "C" void kernel_launch(void* const* d_in, const int* in_sizes, int n_in,
                              void* d_out, int out_size, void* d_ws, size_t ws_size,
                              hipStream_t stream)
{
    const float* x      = (const float*)d_in[0];
    const float* fqk_wQ = (const float*)d_in[1];
    const float* fqk_wK = (const float*)d_in[2];
    const float* fv_w   = (const float*)d_in[3];
    const float* rqk_wQ = (const float*)d_in[4];
    const float* rqk_wK = (const float*)d_in[5];
    const float* rv_w   = (const float*)d_in[6];
    const float* fkn_w  = (const float*)d_in[7];
    const float* rkn_w  = (const float*)d_in[8];
    const float* f_qk   = (const float*)d_in[9];
    const float* f_v    = (const float*)d_in[10];
    const float* r_qk   = (const float*)d_in[11];
    const float* r_v    = (const float*)d_in[12];
    const float* f_know = (const float*)d_in[13];
    const float* r_know = (const float*)d_in[14];
    const float* W_O    = (const float*)d_in[15];
    const float* ln1g   = (const float*)d_in[16];
    const float* ln1b   = (const float*)d_in[17];
    const float* ln2g   = (const float*)d_in[18];
    const float* ln2b   = (const float*)d_in[19];
    float* out_f = (float*)d_out;
    (void)ws_size; (void)in_sizes; (void)n_in; (void)out_size;

    // ---- workspace layout (reused slots) ----
    char* ws = (char*)d_ws;
    const size_t MB = 1024 * 1024;
    bf16_t* rqkT   = (bf16_t*)(ws + 0 * MB);
    bf16_t* rvT    = (bf16_t*)(ws + 4 * MB);
    bf16_t* rknT   = (bf16_t*)(ws + 8 * MB);
    bf16_t* woB    = (bf16_t*)(ws + 10 * MB);
    bf16_t* fknT   = (bf16_t*)(ws + 12 * MB);
    bf16_t* buf_nx = (bf16_t*)(ws + 14 * MB);   // nx -> Vt -> nx2
    bf16_t* buf_y  = (bf16_t*)(ws + 22 * MB);   // y -> QKV
    char*   buf_s  = ws + 54 * MB;
    bf16_t* fqkT   = (bf16_t*)(buf_s);
    bf16_t* fvT    = (bf16_t*)(buf_s + 4 * MB);
    bf16_t* hq     = (bf16_t*)(buf_s);               // [12288][256] stacked h
    bf16_t* hk     = hq + (size_t)4096 * 256;
    bf16_t* hv     = hq + (size_t)8192 * 256;
    bf16_t* attn   = (bf16_t*)(buf_s);
    bf16_t* P0     = (bf16_t*)(buf_s + 16 * MB);
    bf16_t* P0k    = (bf16_t*)(buf_s);
    bf16_t* sk2    = (bf16_t*)(buf_s + 32 * MB);
    bf16_t* Qb     = buf_y;
    bf16_t* Kb     = buf_y + (size_t)4096 * 1024;
    bf16_t* Vb     = buf_y + (size_t)8192 * 1024;
    bf16_t* Vt     = buf_nx;

    const dim3 blk256(256), blk512(512), blkT(32, 8);

    // ---- weight conversion ----
    tcast_kernel<<<dim3(R_DIM / 32, D_DIM / 32, N_NEU), blkT, 0, stream>>>(f_qk, fqkT, D_DIM, R_DIM);
    tcast_kernel<<<dim3(R_DIM / 32, D_DIM / 32, N_NEU), blkT, 0, stream>>>(f_v, fvT, D_DIM, R_DIM);
    tcast_kernel<<<dim3(KR_DIM / 32, D_DIM / 32, N_NEU), blkT, 0, stream>>>(f_know, fknT, D_DIM, KR_DIM);
    tcast_kernel<<<dim3(D_DIM / 32, 2048 / 32, 1), blkT, 0, stream>>>(r_qk, rqkT, 2048, D_DIM);
    tcast_kernel<<<dim3(D_DIM / 32, 2048 / 32, 1), blkT, 0, stream>>>(r_v, rvT, 2048, D_DIM);
    tcast_kernel<<<dim3(D_DIM / 32, 1024 / 32, 1), blkT, 0, stream>>>(r_know, rknT, 1024, D_DIM);
    cast_kernel<<<dim3(1024 * 1024 / 4 / 256), blk256, 0, stream>>>(W_O, woB, 1024 * 1024 / 4);

    // ---- LN1 ----
    ln_kernel<<<dim3(ROWS), blk256, 0, stream>>>(x, ln1g, ln1b, buf_nx);

    // ---- fused feature GEMM: y[4096][4096] (256 blocks, 256x256 tile) ----
    gemm256sq_kernel<<<dim3(16, 16), blk512, 0, stream>>>(buf_nx, fqkT, fqkT, 1 << 30, buf_y, 4096, 4096, 1024);

    // ---- fused weighted sums -> h_q|h_k|h_v [12288][256] (4096 blocks) ----
    wsf_kernel<<<dim3(ROWS), blk256, 0, stream>>>(buf_y, fqk_wQ, fqk_wK, fv_w, hq, hk, hv);

    // ---- restore GEMM with folded wr scaling: QKV[12288][1024] (192 blocks) ----
    gemm_rest_kernel<<<dim3(4, 48), blk512, 0, stream>>>(hq, rqk_wQ, rqk_wK, rv_w, rqkT, rvT, buf_y, 12288, 1024, 2048);

    // ---- V -> Vt ----
    tbf_kernel<<<dim3(D_DIM / 32, S_LEN / 32, B_DIM), blkT, 0, stream>>>(Vb, Vt, S_LEN, D_DIM);

    // ---- attention (512 blocks x 8 waves, Q-tile 128, dbuf gl_lds) ----
    fa_kernel<<<dim3(512), blk512, 0, stream>>>(Qb, Kb, Vt, attn);

    // ---- W_O split-K=2: bf16 partials (256 blocks) ----
    gemm256_kernel<2><<<dim3(8, 16, 2), blk512, 0, stream>>>(attn, woB, woB, 1 << 30, P0, 4096, 1024, 1024);

    // ---- LN2 fused ----
    ln2x_kernel<<<dim3(ROWS), blk256, 0, stream>>>(x, P0, P0 + (size_t)4096 * 1024, ln2g, ln2b, out_f, buf_nx);

    // ---- know feature split-K=2: bf16 partials (256 blocks) ----
    gemm256_kernel<2><<<dim3(8, 16, 2), blk512, 0, stream>>>(buf_nx, fknT, fknT, 1 << 30, P0k, 4096, 1024, 1024);

    // ---- know ws (2048 blocks) ----
    ws2_kernel<<<dim3(ROWS / 2), blk256, 0, stream>>>(P0k, P0k + (size_t)4096 * 1024, fkn_w, rkn_w, sk2);

    // ---- out = sk2 @ rknT^T + x2 -> d_out ----
    gemm_kernel<1><<<dim3(8, 32), blk256, 0, stream>>>(sk2, rknT, rknT, 1 << 30, d_out, out_f, 4096, 1024, 1024);
}